// Round 5
// baseline (265.232 us; speedup 1.0000x reference)
//
#include <hip/hip_runtime.h>
#include <hip/hip_bf16.h>
#include <cstdint>

#define BATCH 4096
#define LAT   2048
#define NFREQ 2074
#define KPAD  2112   // NFREQ padded up to a multiple of 64 (zero-filled); 66 K-iters

typedef __bf16 bf16x8 __attribute__((ext_vector_type(8)));
typedef float  f32x4  __attribute__((ext_vector_type(4)));

__device__ __forceinline__ unsigned short f2bf(float f) {
    unsigned int u = __float_as_uint(f);
    u = (u + 0x7fffu + ((u >> 16) & 1u)) >> 16;
    return (unsigned short)u;
}

__device__ __forceinline__ void gload_lds16(const unsigned short* g, unsigned short* l) {
    __builtin_amdgcn_global_load_lds(
        (const __attribute__((address_space(1))) unsigned int*)g,
        (__attribute__((address_space(3))) unsigned int*)l,
        16, 0, 0);
}

// ---------------------------------------------------------------------------
// prep: blocks [0,4096)    -> cast x fp32 -> bf16 (8 elem/thread) + init max/cnt
//       blocks [4096,5152) -> transpose+cast W  -> WT  [LAT][KPAD]
//       blocks [5152,6208) -> transpose+cast cb -> cosT[LAT][KPAD]
// Round-4: transpose path vectorized (float4 loads 16B/lane, ushort4 stores
// 8B/lane -- was scalar 4B/2B, Common-mistake #2). LDS access <=2-way (free).
__global__ void prep_kernel(const float* __restrict__ x,
                            const float* __restrict__ W,
                            const float* __restrict__ cb,
                            unsigned short* __restrict__ xb,
                            unsigned short* __restrict__ WT,
                            unsigned short* __restrict__ cosT,
                            float* __restrict__ maxp,
                            int* __restrict__ cnt) {
    __shared__ float t[64][65];
    const int bid = blockIdx.x;
    const int tid = threadIdx.x;
    if (bid < 4096) {
        int i = bid * 256 + tid;
        const float4* x4 = (const float4*)x;
        float4 a = x4[2 * i];
        float4 b = x4[2 * i + 1];
        union { unsigned short us[8]; uint4 v; } p;
        p.us[0] = f2bf(a.x); p.us[1] = f2bf(a.y); p.us[2] = f2bf(a.z); p.us[3] = f2bf(a.w);
        p.us[4] = f2bf(b.x); p.us[5] = f2bf(b.y); p.us[6] = f2bf(b.z); p.us[7] = f2bf(b.w);
        ((uint4*)xb)[i] = p.v;
        if (i == 0) { *maxp = -__builtin_inff(); *cnt = 0; }
        return;
    }
    int b2 = bid - 4096;
    const float* in     = (b2 < 1056) ? W  : cb;
    unsigned short* out = (b2 < 1056) ? WT : cosT;
    if (b2 >= 1056) b2 -= 1056;
    const int c0 = (b2 % 32) * 64;
    const int r0 = (b2 / 32) * 64;
    // load 64x64 fp32 tile, float4 per lane (rows of 'in')
    for (int i = tid; i < 1024; i += 256) {
        int rr = i >> 4;            // 0..63
        int c4 = (i & 15) * 4;      // 0..60
        int r  = r0 + rr;
        float4 v;
        if (r < NFREQ) v = *(const float4*)&in[(size_t)r * LAT + c0 + c4];
        else           v = make_float4(0.f, 0.f, 0.f, 0.f);
        t[rr][c4 + 0] = v.x; t[rr][c4 + 1] = v.y;
        t[rr][c4 + 2] = v.z; t[rr][c4 + 3] = v.w;
    }
    __syncthreads();
    // store transposed, ushort4 per lane (rows of 'out' = cols of 'in')
    for (int i = tid; i < 1024; i += 256) {
        int cc = i >> 4;            // 0..63: out row
        int r4 = (i & 15) * 4;      // 0..60: out col group
        ushort4 o;
        o.x = f2bf(t[r4 + 0][cc]); o.y = f2bf(t[r4 + 1][cc]);
        o.z = f2bf(t[r4 + 2][cc]); o.w = f2bf(t[r4 + 3][cc]);
        *(ushort4*)&out[(size_t)(c0 + cc) * KPAD + r0 + r4] = o;
    }
}

// ---------------------------------------------------------------------------
// LDS chunk swizzle (verified rounds 2-3: conflicts 6.29M -> 0): store logical
// 16B chunk c of row r at physical c ^ ((r>>1)&3), both-sides (pre-swizzled
// global_load_lds source + same XOR on ds_read address).
//
// Post-mortems baked in:
//  - r2/r3: LDS conflicts and LDS BW are NOT the gemm2 bottleneck. 653 TF =
//    the documented 2-phase-structure plateau; TLP moved the needle (round-0
//    16 waves/CU fastest) -> gemm2 is 8-wave blocks + swizzle.
//  - r3: depth-2 counted vmcnt alone = null; depth-1/S=3 retained.
//  - r1: hipLaunchCooperativeKernel is graph-capture-illegal. Grid sync in
//    gemm2 is a hand-rolled atomic-counter barrier: grid 512 = 2 blocks/CU
//    co-resident BY CONSTRUCTION (LDS 48.5KB -> 3/CU cap, bounds (512,4) ->
//    2/CU, capacity 512+). Deadlock-proof: bounded spin + per-block flags
//    fallback fixed by the flag-gated scale kernel.
//  - r4: container infra flake (no pytest ran); design unchanged, resubmitted.

// GEMM1: C[m][n] = sum_k A[m][k]*Bt[n][k], bf16 out.
// 128x64 block tile, 4 waves (2m x 2n of 64x32 wave tiles), BK=32, 3-stage
// circular LDS, vmcnt(3) straddle. Grid 512 = 2 blocks/CU.
template <int N, int K>
__global__ __launch_bounds__(256, 2)
void gemm1_kernel(const unsigned short* __restrict__ A,
                  const unsigned short* __restrict__ Bt,
                  unsigned short* __restrict__ C) {
    __shared__ alignas(16) unsigned short As[3][128 * 32];
    __shared__ alignas(16) unsigned short Bs[3][64 * 32];

    const int tid  = threadIdx.x;
    const int wave = tid >> 6;
    const int lane = tid & 63;
    const int wm   = (wave >> 1) * 64;
    const int wn   = (wave & 1) * 32;
    const int quad = lane >> 4;
    const int l16  = lane & 15;

    const int mBase = blockIdx.y * 128;
    const int nBase = blockIdx.x * 64;

    const int srow = lane >> 2;                              // row within 16-row chunk
    const int sk   = (((lane & 3) ^ ((srow >> 1) & 3))) * 8; // swizzled k-offset (elems)

    const unsigned short* Ab1 = A  + (size_t)(mBase + (wave * 2 + 0) * 16 + srow) * K + sk;
    const unsigned short* Ab2 = A  + (size_t)(mBase + (wave * 2 + 1) * 16 + srow) * K + sk;
    const unsigned short* Bb1 = Bt + (size_t)(nBase + wave * 16 + srow) * K + sk;

    const int aoff1 = ((wave * 2 + 0) * 16) * 32;
    const int aoff2 = ((wave * 2 + 1) * 16) * 32;
    const int boff  = (wave * 16) * 32;

    // fragment-read physical chunk: quad ^ ((row>>1)&3); row = <mult of 16> + l16
    const int pc = (quad ^ ((l16 >> 1) & 3)) * 8;

    constexpr int NIT = K / 32;
    gload_lds16(Ab1, &As[0][aoff1]);
    gload_lds16(Ab2, &As[0][aoff2]);
    gload_lds16(Bb1, &Bs[0][boff]);

    f32x4 acc[4][2] = {};
    int bc = 0;
    for (int j = 0; j < NIT; ++j) {
        const int bn = (bc == 2) ? 0 : bc + 1;
        if (j + 1 < NIT) {
            const int k0 = (j + 1) * 32;
            gload_lds16(Ab1 + k0, &As[bn][aoff1]);
            gload_lds16(Ab2 + k0, &As[bn][aoff2]);
            gload_lds16(Bb1 + k0, &Bs[bn][boff]);
            asm volatile("s_waitcnt vmcnt(3)\n\ts_barrier" ::: "memory");
        } else {
            asm volatile("s_waitcnt vmcnt(0)\n\ts_barrier" ::: "memory");
        }
        bf16x8 af[4], bfr[2];
#pragma unroll
        for (int mi = 0; mi < 4; ++mi)
            af[mi] = *(const bf16x8*)&As[bc][(wm + mi * 16 + l16) * 32 + pc];
#pragma unroll
        for (int ni = 0; ni < 2; ++ni)
            bfr[ni] = *(const bf16x8*)&Bs[bc][(wn + ni * 16 + l16) * 32 + pc];
#pragma unroll
        for (int mi = 0; mi < 4; ++mi)
#pragma unroll
            for (int ni = 0; ni < 2; ++ni)
                acc[mi][ni] = __builtin_amdgcn_mfma_f32_16x16x32_bf16(
                    af[mi], bfr[ni], acc[mi][ni], 0, 0, 0);
        bc = bn;
    }

    // C/D layout: col = lane&15, row = quad*4 + reg
#pragma unroll
    for (int mi = 0; mi < 4; ++mi)
#pragma unroll
        for (int ni = 0; ni < 2; ++ni) {
            int col = nBase + wn + ni * 16 + l16;
#pragma unroll
            for (int r = 0; r < 4; ++r) {
                int row = mBase + wm + mi * 16 + quad * 4 + r;
                C[(size_t)row * N + col] = f2bf(acc[mi][ni][r]);
            }
        }
}

// ---------------------------------------------------------------------------
// GEMM2: out[m][n] = sum_k A[m][k]*Bt[n][k], fp32 out, fused global max AND
// fused scale via software grid barrier. Round-0 structure (fastest measured:
// 512 thr = 8 waves of 64x32, 16 waves/CU) + swizzle (conflicts -> 0).
// 3-stage circular LDS, vmcnt(2) straddle (1 A + 1 B DMA per wave per iter).
// After K-loop: block max -> one atomic -> release fence -> counter inc ->
// bounded spin until all 512 blocks arrive -> scaled store (flag=1).
// Timeout fallback: unscaled store (flag=0), fixed by scale_kernel.
template <int N, int K>
__global__ __launch_bounds__(512, 4)
void gemm2_kernel(const unsigned short* __restrict__ A,
                  const unsigned short* __restrict__ Bt,
                  float* __restrict__ C,
                  float* __restrict__ maxp,
                  int* __restrict__ cnt,
                  int* __restrict__ flags) {
    __shared__ alignas(16) unsigned short As[3][128 * 32];
    __shared__ alignas(16) unsigned short Bs[3][128 * 32];
    __shared__ float redbuf[8];
    __shared__ float s_inv;

    const int tid  = threadIdx.x;
    const int wave = tid >> 6;          // 0..7
    const int lane = tid & 63;
    const int wm   = (wave >> 2) * 64;  // m-half
    const int wn   = (wave & 3) * 32;   // n-quarter
    const int quad = lane >> 4;
    const int l16  = lane & 15;

    const int mBase = blockIdx.y * 128;
    const int nBase = blockIdx.x * 128;

    const int srow = lane >> 2;
    const int sk   = (((lane & 3) ^ ((srow >> 1) & 3))) * 8; // swizzled source

    const unsigned short* Ab1 = A  + (size_t)(mBase + wave * 16 + srow) * K + sk;
    const unsigned short* Bb1 = Bt + (size_t)(nBase + wave * 16 + srow) * K + sk;
    const int coff = (wave * 16) * 32;

    const int pc = (quad ^ ((l16 >> 1) & 3)) * 8;            // swizzled frag read

    constexpr int NIT = K / 32;
    gload_lds16(Ab1, &As[0][coff]);
    gload_lds16(Bb1, &Bs[0][coff]);

    f32x4 acc[4][2] = {};
    int bc = 0;
    for (int j = 0; j < NIT; ++j) {
        const int bn = (bc == 2) ? 0 : bc + 1;
        if (j + 1 < NIT) {
            const int k0 = (j + 1) * 32;
            gload_lds16(Ab1 + k0, &As[bn][coff]);
            gload_lds16(Bb1 + k0, &Bs[bn][coff]);
            asm volatile("s_waitcnt vmcnt(2)\n\ts_barrier" ::: "memory");
        } else {
            asm volatile("s_waitcnt vmcnt(0)\n\ts_barrier" ::: "memory");
        }
        bf16x8 af[4], bfr[2];
#pragma unroll
        for (int mi = 0; mi < 4; ++mi)
            af[mi] = *(const bf16x8*)&As[bc][(wm + mi * 16 + l16) * 32 + pc];
#pragma unroll
        for (int ni = 0; ni < 2; ++ni)
            bfr[ni] = *(const bf16x8*)&Bs[bc][(wn + ni * 16 + l16) * 32 + pc];
#pragma unroll
        for (int mi = 0; mi < 4; ++mi)
#pragma unroll
            for (int ni = 0; ni < 2; ++ni)
                acc[mi][ni] = __builtin_amdgcn_mfma_f32_16x16x32_bf16(
                    af[mi], bfr[ni], acc[mi][ni], 0, 0, 0);
        bc = bn;
    }

    // block max (acc stays in regs; out written once, scaled, after barrier)
    float vmax = -__builtin_inff();
#pragma unroll
    for (int mi = 0; mi < 4; ++mi)
#pragma unroll
        for (int ni = 0; ni < 2; ++ni)
#pragma unroll
            for (int r = 0; r < 4; ++r)
                vmax = fmaxf(vmax, acc[mi][ni][r]);
#pragma unroll
    for (int off = 32; off > 0; off >>= 1)
        vmax = fmaxf(vmax, __shfl_xor(vmax, off));
    if (lane == 0) redbuf[wave] = vmax;
    __syncthreads();
    if (tid == 0) {
        float m = redbuf[0];
#pragma unroll
        for (int w = 1; w < 8; ++w) m = fmaxf(m, redbuf[w]);
        if (m >= 0.0f) atomicMax((int*)maxp, __float_as_int(m));
        else           atomicMin((unsigned int*)maxp, __float_as_uint(m));
        __threadfence();  // release our max before announcing arrival
        __hip_atomic_fetch_add(cnt, 1, __ATOMIC_ACQ_REL, __HIP_MEMORY_SCOPE_AGENT);
        const int total = gridDim.x * gridDim.y;   // 512
        int ok = 0;
        for (int it = 0; it < 30000; ++it) {       // bounded: no deadlock (<~7ms)
            if (__hip_atomic_load(cnt, __ATOMIC_ACQUIRE,
                                  __HIP_MEMORY_SCOPE_AGENT) >= total) { ok = 1; break; }
            __builtin_amdgcn_s_sleep(8);
        }
        float mx = __int_as_float(
            __hip_atomic_load((int*)maxp, __ATOMIC_RELAXED, __HIP_MEMORY_SCOPE_AGENT));
        s_inv = ok ? (1.0f / mx) : 1.0f;           // fallback: store unscaled
        flags[blockIdx.y * gridDim.x + blockIdx.x] = ok;
    }
    __syncthreads();
    const float inv = s_inv;

    // single scaled store of the output tile
#pragma unroll
    for (int mi = 0; mi < 4; ++mi)
#pragma unroll
        for (int ni = 0; ni < 2; ++ni) {
            int col = nBase + wn + ni * 16 + l16;
#pragma unroll
            for (int r = 0; r < 4; ++r) {
                int row = mBase + wm + mi * 16 + quad * 4 + r;
                C[(size_t)row * N + col] = acc[mi][ni][r] * inv;
            }
        }
}

// ---------------------------------------------------------------------------
// flag-gated fixup: good path touches only the 2KB flag array (blocks whose
// gemm2 tile already stored scaled values return immediately).
__global__ void scale_kernel(float* __restrict__ out, const float* __restrict__ maxp,
                             const int* __restrict__ flags) {
    int i = blockIdx.x * blockDim.x + threadIdx.x;
    int e   = i * 4;
    int row = e >> 11;          // N = 2048 cols
    int col = e & 2047;
    int gbid = (row >> 7) * (LAT / 128) + (col >> 7);  // gemm2 grid: x=16 n-tiles
    if (flags[gbid]) return;    // already scaled by gemm2
    float inv = 1.0f / (*maxp);
    float4* o4 = (float4*)out;
    float4 v = o4[i];
    v.x *= inv; v.y *= inv; v.z *= inv; v.w *= inv;
    o4[i] = v;
}

// ---------------------------------------------------------------------------
extern "C" void kernel_launch(void* const* d_in, const int* in_sizes, int n_in,
                              void* d_out, int out_size, void* d_ws, size_t ws_size,
                              hipStream_t stream) {
    const float* x  = (const float*)d_in[0];  // (4096, 2048)
    const float* W  = (const float*)d_in[1];  // (2074, 2048)
    const float* cb = (const float*)d_in[2];  // (2074, 2048)

    char* ws = (char*)d_ws;
    unsigned short* xb   = (unsigned short*)ws;                                   // [4096][2048] bf16
    unsigned short* WT   = (unsigned short*)(ws + (size_t)BATCH * LAT * 2);       // [2048][2112] bf16
    unsigned short* cosT = (unsigned short*)((char*)WT + (size_t)LAT * KPAD * 2);
    unsigned short* C1   = (unsigned short*)((char*)cosT + (size_t)LAT * KPAD * 2); // [2048][2048] bf16
    float*          maxp = (float*)((char*)C1 + (size_t)LAT * LAT * 2);
    int*            cnt   = (int*)(maxp + 1);
    int*            flags = (int*)(maxp + 2);                                     // [512]
    float*          out  = (float*)d_out;

    // 1. fused prep: cast x -> bf16 (+init max/cnt), transpose+cast W and cos_basis
    prep_kernel<<<4096 + 2 * 1056, 256, 0, stream>>>(x, W, cb, xb, WT, cosT, maxp, cnt);

    // 2. C1[l2][l1] = sum_f cosT[l2,f] * WT[l1,f]   (128x64 tiles, 512 blocks)
    gemm1_kernel<LAT, KPAD>
        <<<dim3(LAT / 64, LAT / 128), 256, 0, stream>>>(cosT, WT, C1);

    // 3. out[b][l2] = sum_l1 xb[b][l1] * C1[l2][l1]  (128x128, 512 thr, 8 waves,
    //    fused max + software grid barrier + fused scale)
    gemm2_kernel<LAT, LAT>
        <<<dim3(LAT / 128, BATCH / 128), 512, 0, stream>>>(xb, C1, out, maxp, cnt, flags);

    // 4. flag-gated fixup (no-op traffic when the in-kernel barrier succeeded)
    scale_kernel<<<(out_size / 4) / 256, 256, 0, stream>>>(out, maxp, flags);
}

// Round 6
// 200.380 us; speedup vs baseline: 1.3236x; 1.3236x over previous
//
#include <hip/hip_runtime.h>
#include <hip/hip_bf16.h>
#include <cstdint>

#define BATCH 4096
#define LAT   2048
#define NFREQ 2074
#define KPAD  2112   // NFREQ padded up to a multiple of 64 (zero-filled); 66 K-iters

typedef __bf16 bf16x8 __attribute__((ext_vector_type(8)));
typedef float  f32x4  __attribute__((ext_vector_type(4)));

__device__ __forceinline__ unsigned short f2bf(float f) {
    unsigned int u = __float_as_uint(f);
    u = (u + 0x7fffu + ((u >> 16) & 1u)) >> 16;
    return (unsigned short)u;
}

__device__ __forceinline__ void gload_lds16(const unsigned short* g, unsigned short* l) {
    __builtin_amdgcn_global_load_lds(
        (const __attribute__((address_space(1))) unsigned int*)g,
        (__attribute__((address_space(3))) unsigned int*)l,
        16, 0, 0);
}

// ---------------------------------------------------------------------------
// prep: blocks [0,4096)    -> cast x fp32 -> bf16 (8 elem/thread) + init max
//       blocks [4096,5152) -> transpose+cast W  -> WT  [LAT][KPAD]
//       blocks [5152,6208) -> transpose+cast cb -> cosT[LAT][KPAD]
// Transpose path vectorized (float4 loads 16B/lane, ushort4 stores 8B/lane);
// correctness validated in round 5.
__global__ void prep_kernel(const float* __restrict__ x,
                            const float* __restrict__ W,
                            const float* __restrict__ cb,
                            unsigned short* __restrict__ xb,
                            unsigned short* __restrict__ WT,
                            unsigned short* __restrict__ cosT,
                            float* __restrict__ maxp) {
    __shared__ float t[64][65];
    const int bid = blockIdx.x;
    const int tid = threadIdx.x;
    if (bid < 4096) {
        int i = bid * 256 + tid;
        const float4* x4 = (const float4*)x;
        float4 a = x4[2 * i];
        float4 b = x4[2 * i + 1];
        union { unsigned short us[8]; uint4 v; } p;
        p.us[0] = f2bf(a.x); p.us[1] = f2bf(a.y); p.us[2] = f2bf(a.z); p.us[3] = f2bf(a.w);
        p.us[4] = f2bf(b.x); p.us[5] = f2bf(b.y); p.us[6] = f2bf(b.z); p.us[7] = f2bf(b.w);
        ((uint4*)xb)[i] = p.v;
        if (i == 0) *maxp = -__builtin_inff();
        return;
    }
    int b2 = bid - 4096;
    const float* in     = (b2 < 1056) ? W  : cb;
    unsigned short* out = (b2 < 1056) ? WT : cosT;
    if (b2 >= 1056) b2 -= 1056;
    const int c0 = (b2 % 32) * 64;
    const int r0 = (b2 / 32) * 64;
    for (int i = tid; i < 1024; i += 256) {
        int rr = i >> 4;            // 0..63
        int c4 = (i & 15) * 4;      // 0..60
        int r  = r0 + rr;
        float4 v;
        if (r < NFREQ) v = *(const float4*)&in[(size_t)r * LAT + c0 + c4];
        else           v = make_float4(0.f, 0.f, 0.f, 0.f);
        t[rr][c4 + 0] = v.x; t[rr][c4 + 1] = v.y;
        t[rr][c4 + 2] = v.z; t[rr][c4 + 3] = v.w;
    }
    __syncthreads();
    for (int i = tid; i < 1024; i += 256) {
        int cc = i >> 4;            // 0..63: out row
        int r4 = (i & 15) * 4;      // 0..60: out col group
        ushort4 o;
        o.x = f2bf(t[r4 + 0][cc]); o.y = f2bf(t[r4 + 1][cc]);
        o.z = f2bf(t[r4 + 2][cc]); o.w = f2bf(t[r4 + 3][cc]);
        *(ushort4*)&out[(size_t)(c0 + cc) * KPAD + r0 + r4] = o;
    }
}

// ---------------------------------------------------------------------------
// LDS chunk swizzle (verified r2-r3: conflicts 6.29M -> 0): store logical 16B
// chunk c of row r at physical c ^ ((r>>1)&3), both-sides (pre-swizzled
// global_load_lds source + same XOR on ds_read address).
//
// Ledger of post-mortems baked into this round:
//  - r2/r3: LDS conflicts / LDS BW are NOT the gemm2 limit. Three configs all
//    ~51us = the documented 2-phase plateau (m230/m233/m248).
//  - r3: counted vmcnt WITHOUT phase-split = null (matches m218: T4 needs T3).
//  - r5: software grid barrier at exact-capacity occupancy = +80us (block
//    start stagger + 512 cross-XCD spinners). Grid sync is OFF LIMITS; scale
//    stays a separate dispatch. (r1: cooperative launch graph-illegal too.)
//  - r6 (this): gemm2 K-loop ported to the guide's phase rhythm: 2 phases per
//    K=32 step, 4 LDS buffers, depth-2 prefetch, counted vmcnt(3) (never 0 in
//    steady state), setprio(1) around MFMA clusters (T5 has its T3 prereq
//    now), sched_barrier(0) pins (rule #18).

// GEMM1: C[m][n] = sum_k A[m][k]*Bt[n][k], bf16 out.
// 128x64 block tile, 4 waves (2m x 2n of 64x32 wave tiles), BK=32, 3-stage
// circular LDS, vmcnt(3) straddle. Grid 512 = 2 blocks/CU. (Unchanged.)
template <int N, int K>
__global__ __launch_bounds__(256, 2)
void gemm1_kernel(const unsigned short* __restrict__ A,
                  const unsigned short* __restrict__ Bt,
                  unsigned short* __restrict__ C) {
    __shared__ alignas(16) unsigned short As[3][128 * 32];
    __shared__ alignas(16) unsigned short Bs[3][64 * 32];

    const int tid  = threadIdx.x;
    const int wave = tid >> 6;
    const int lane = tid & 63;
    const int wm   = (wave >> 1) * 64;
    const int wn   = (wave & 1) * 32;
    const int quad = lane >> 4;
    const int l16  = lane & 15;

    const int mBase = blockIdx.y * 128;
    const int nBase = blockIdx.x * 64;

    const int srow = lane >> 2;                              // row within 16-row chunk
    const int sk   = (((lane & 3) ^ ((srow >> 1) & 3))) * 8; // swizzled k-offset (elems)

    const unsigned short* Ab1 = A  + (size_t)(mBase + (wave * 2 + 0) * 16 + srow) * K + sk;
    const unsigned short* Ab2 = A  + (size_t)(mBase + (wave * 2 + 1) * 16 + srow) * K + sk;
    const unsigned short* Bb1 = Bt + (size_t)(nBase + wave * 16 + srow) * K + sk;

    const int aoff1 = ((wave * 2 + 0) * 16) * 32;
    const int aoff2 = ((wave * 2 + 1) * 16) * 32;
    const int boff  = (wave * 16) * 32;

    const int pc = (quad ^ ((l16 >> 1) & 3)) * 8;

    constexpr int NIT = K / 32;
    gload_lds16(Ab1, &As[0][aoff1]);
    gload_lds16(Ab2, &As[0][aoff2]);
    gload_lds16(Bb1, &Bs[0][boff]);

    f32x4 acc[4][2] = {};
    int bc = 0;
    for (int j = 0; j < NIT; ++j) {
        const int bn = (bc == 2) ? 0 : bc + 1;
        if (j + 1 < NIT) {
            const int k0 = (j + 1) * 32;
            gload_lds16(Ab1 + k0, &As[bn][aoff1]);
            gload_lds16(Ab2 + k0, &As[bn][aoff2]);
            gload_lds16(Bb1 + k0, &Bs[bn][boff]);
            asm volatile("s_waitcnt vmcnt(3)\n\ts_barrier" ::: "memory");
        } else {
            asm volatile("s_waitcnt vmcnt(0)\n\ts_barrier" ::: "memory");
        }
        bf16x8 af[4], bfr[2];
#pragma unroll
        for (int mi = 0; mi < 4; ++mi)
            af[mi] = *(const bf16x8*)&As[bc][(wm + mi * 16 + l16) * 32 + pc];
#pragma unroll
        for (int ni = 0; ni < 2; ++ni)
            bfr[ni] = *(const bf16x8*)&Bs[bc][(wn + ni * 16 + l16) * 32 + pc];
#pragma unroll
        for (int mi = 0; mi < 4; ++mi)
#pragma unroll
            for (int ni = 0; ni < 2; ++ni)
                acc[mi][ni] = __builtin_amdgcn_mfma_f32_16x16x32_bf16(
                    af[mi], bfr[ni], acc[mi][ni], 0, 0, 0);
        bc = bn;
    }

#pragma unroll
    for (int mi = 0; mi < 4; ++mi)
#pragma unroll
        for (int ni = 0; ni < 2; ++ni) {
            int col = nBase + wn + ni * 16 + l16;
#pragma unroll
            for (int r = 0; r < 4; ++r) {
                int row = mBase + wm + mi * 16 + quad * 4 + r;
                C[(size_t)row * N + col] = f2bf(acc[mi][ni][r]);
            }
        }
}

// ---------------------------------------------------------------------------
// GEMM2: out[m][n] = sum_k A[m][k]*Bt[n][k], fp32 out + fused global max.
// Round-0 geometry (fastest measured: 512 thr = 8 waves of 64x32, 16 waves/
// CU) + verified swizzle, K-loop rebuilt as the guide's phase rhythm:
//   4 LDS buffers (read j&3, write (j+2)&3 -- never aliased), depth-2
//   prefetch; per K=32 step, 2 phases:
//     phase A: issue A-chunk DMA for tile j+2; vmcnt(3) retires exactly tile
//              j (outstanding: t_j:2, t_{j+1}:2, t_{j+2}A:1); barrier;
//              ds_read a0,a1,b0,b1; setprio(1) 4 MFMA setprio(0); barrier.
//     phase B: issue B-chunk DMA for tile j+2; ds_read a2,a3;
//              setprio(1) 4 MFMA setprio(0); barrier.
//   vmcnt never drains to 0 in steady state (T4); epilogue 2 -> 0.
// LDS 64KB -> 2 blocks/CU. Max: wave-reduce -> LDS -> ONE atomic per block.
template <int N, int K>
__global__ __launch_bounds__(512, 4)
void gemm2_kernel(const unsigned short* __restrict__ A,
                  const unsigned short* __restrict__ Bt,
                  float* __restrict__ C,
                  float* __restrict__ maxp) {
    __shared__ alignas(16) unsigned short As[4][128 * 32];
    __shared__ alignas(16) unsigned short Bs[4][128 * 32];
    __shared__ float redbuf[8];

    const int tid  = threadIdx.x;
    const int wave = tid >> 6;          // 0..7
    const int lane = tid & 63;
    const int wm   = (wave >> 2) * 64;  // m-half
    const int wn   = (wave & 3) * 32;   // n-quarter
    const int quad = lane >> 4;
    const int l16  = lane & 15;

    const int mBase = blockIdx.y * 128;
    const int nBase = blockIdx.x * 128;

    const int srow = lane >> 2;
    const int sk   = (((lane & 3) ^ ((srow >> 1) & 3))) * 8; // swizzled source

    const unsigned short* Ab1 = A  + (size_t)(mBase + wave * 16 + srow) * K + sk;
    const unsigned short* Bb1 = Bt + (size_t)(nBase + wave * 16 + srow) * K + sk;
    const int coff = (wave * 16) * 32;

    const int pc = (quad ^ ((l16 >> 1) & 3)) * 8;            // swizzled frag read

    constexpr int NIT = K / 32;   // 64
    // prologue: tiles 0 and 1 (depth-2); per-wave order: t0A,t0B,t1A,t1B
    gload_lds16(Ab1,      &As[0][coff]);
    gload_lds16(Bb1,      &Bs[0][coff]);
    gload_lds16(Ab1 + 32, &As[1][coff]);
    gload_lds16(Bb1 + 32, &Bs[1][coff]);

    f32x4 acc[4][2] = {};
    for (int j = 0; j < NIT; ++j) {
        const int c = j & 3;
        const int s = (j + 2) & 3;
        // ---------------- phase A ----------------
        if (j + 2 < NIT) {
            gload_lds16(Ab1 + (j + 2) * 32, &As[s][coff]);
            asm volatile("s_waitcnt vmcnt(3)\n\ts_barrier" ::: "memory");
        } else if (j + 1 < NIT) {
            asm volatile("s_waitcnt vmcnt(2)\n\ts_barrier" ::: "memory");
        } else {
            asm volatile("s_waitcnt vmcnt(0)\n\ts_barrier" ::: "memory");
        }
        bf16x8 a0 = *(const bf16x8*)&As[c][(wm +  0 + l16) * 32 + pc];
        bf16x8 a1 = *(const bf16x8*)&As[c][(wm + 16 + l16) * 32 + pc];
        bf16x8 b0 = *(const bf16x8*)&Bs[c][(wn +  0 + l16) * 32 + pc];
        bf16x8 b1 = *(const bf16x8*)&Bs[c][(wn + 16 + l16) * 32 + pc];
        __builtin_amdgcn_s_setprio(1);
        acc[0][0] = __builtin_amdgcn_mfma_f32_16x16x32_bf16(a0, b0, acc[0][0], 0, 0, 0);
        acc[0][1] = __builtin_amdgcn_mfma_f32_16x16x32_bf16(a0, b1, acc[0][1], 0, 0, 0);
        acc[1][0] = __builtin_amdgcn_mfma_f32_16x16x32_bf16(a1, b0, acc[1][0], 0, 0, 0);
        acc[1][1] = __builtin_amdgcn_mfma_f32_16x16x32_bf16(a1, b1, acc[1][1], 0, 0, 0);
        __builtin_amdgcn_s_setprio(0);
        __builtin_amdgcn_sched_barrier(0);                   // pin MFMA cluster
        asm volatile("s_barrier" ::: "memory");
        // ---------------- phase B ----------------
        if (j + 2 < NIT)
            gload_lds16(Bb1 + (j + 2) * 32, &Bs[s][coff]);
        bf16x8 a2 = *(const bf16x8*)&As[c][(wm + 32 + l16) * 32 + pc];
        bf16x8 a3 = *(const bf16x8*)&As[c][(wm + 48 + l16) * 32 + pc];
        __builtin_amdgcn_s_setprio(1);
        acc[2][0] = __builtin_amdgcn_mfma_f32_16x16x32_bf16(a2, b0, acc[2][0], 0, 0, 0);
        acc[2][1] = __builtin_amdgcn_mfma_f32_16x16x32_bf16(a2, b1, acc[2][1], 0, 0, 0);
        acc[3][0] = __builtin_amdgcn_mfma_f32_16x16x32_bf16(a3, b0, acc[3][0], 0, 0, 0);
        acc[3][1] = __builtin_amdgcn_mfma_f32_16x16x32_bf16(a3, b1, acc[3][1], 0, 0, 0);
        __builtin_amdgcn_s_setprio(0);
        __builtin_amdgcn_sched_barrier(0);                   // pin MFMA cluster
        asm volatile("s_barrier" ::: "memory");
    }

    // epilogue: fp32 store + block max + one atomic
    float vmax = -__builtin_inff();
#pragma unroll
    for (int mi = 0; mi < 4; ++mi)
#pragma unroll
        for (int ni = 0; ni < 2; ++ni) {
            int col = nBase + wn + ni * 16 + l16;
#pragma unroll
            for (int r = 0; r < 4; ++r) {
                int row = mBase + wm + mi * 16 + quad * 4 + r;
                float v = acc[mi][ni][r];
                C[(size_t)row * N + col] = v;
                vmax = fmaxf(vmax, v);
            }
        }
#pragma unroll
    for (int off = 32; off > 0; off >>= 1)
        vmax = fmaxf(vmax, __shfl_xor(vmax, off));
    if (lane == 0) redbuf[wave] = vmax;
    __syncthreads();
    if (tid == 0) {
        float m = redbuf[0];
#pragma unroll
        for (int w = 1; w < 8; ++w) m = fmaxf(m, redbuf[w]);
        if (m >= 0.0f) atomicMax((int*)maxp, __float_as_int(m));
        else           atomicMin((unsigned int*)maxp, __float_as_uint(m));
    }
}

// ---------------------------------------------------------------------------
__global__ void scale_kernel(float* __restrict__ out, const float* __restrict__ maxp) {
    int i = blockIdx.x * blockDim.x + threadIdx.x;
    float inv = 1.0f / (*maxp);
    float4* o4 = (float4*)out;
    float4 v = o4[i];
    v.x *= inv; v.y *= inv; v.z *= inv; v.w *= inv;
    o4[i] = v;
}

// ---------------------------------------------------------------------------
extern "C" void kernel_launch(void* const* d_in, const int* in_sizes, int n_in,
                              void* d_out, int out_size, void* d_ws, size_t ws_size,
                              hipStream_t stream) {
    const float* x  = (const float*)d_in[0];  // (4096, 2048)
    const float* W  = (const float*)d_in[1];  // (2074, 2048)
    const float* cb = (const float*)d_in[2];  // (2074, 2048)

    char* ws = (char*)d_ws;
    unsigned short* xb   = (unsigned short*)ws;                                   // [4096][2048] bf16
    unsigned short* WT   = (unsigned short*)(ws + (size_t)BATCH * LAT * 2);       // [2048][2112] bf16
    unsigned short* cosT = (unsigned short*)((char*)WT + (size_t)LAT * KPAD * 2);
    unsigned short* C1   = (unsigned short*)((char*)cosT + (size_t)LAT * KPAD * 2); // [2048][2048] bf16
    float*          maxp = (float*)((char*)C1 + (size_t)LAT * LAT * 2);
    float*          out  = (float*)d_out;

    // 1. fused prep: cast x -> bf16 (+init max), transpose+cast W and cos_basis
    prep_kernel<<<4096 + 2 * 1056, 256, 0, stream>>>(x, W, cb, xb, WT, cosT, maxp);

    // 2. C1[l2][l1] = sum_f cosT[l2,f] * WT[l1,f]   (128x64 tiles, 512 blocks)
    gemm1_kernel<LAT, KPAD>
        <<<dim3(LAT / 64, LAT / 128), 256, 0, stream>>>(cosT, WT, C1);

    // 3. out[b][l2] = sum_l1 xb[b][l1] * C1[l2][l1]  (128x128, 512 thr, 8 waves,
    //    2-phase-per-K32 schedule, fused max)
    gemm2_kernel<LAT, LAT>
        <<<dim3(LAT / 128, BATCH / 128), 512, 0, stream>>>(xb, C1, out, maxp);

    // 4. out /= max
    scale_kernel<<<(out_size / 4) / 256, 256, 0, stream>>>(out, maxp);
}

// Round 8
// 191.617 us; speedup vs baseline: 1.3842x; 1.0457x over previous
//
#include <hip/hip_runtime.h>
#include <hip/hip_bf16.h>
#include <cstdint>

#define BATCH 4096
#define LAT   2048
#define NFREQ 2074
#define KPAD  2112   // NFREQ padded up to a multiple of 64 (zero-filled); 66 K-iters

typedef __bf16 bf16x8 __attribute__((ext_vector_type(8)));
typedef float  f32x4  __attribute__((ext_vector_type(4)));

__device__ __forceinline__ unsigned short f2bf(float f) {
    unsigned int u = __float_as_uint(f);
    u = (u + 0x7fffu + ((u >> 16) & 1u)) >> 16;
    return (unsigned short)u;
}

__device__ __forceinline__ void gload_lds16(const unsigned short* g, unsigned short* l) {
    __builtin_amdgcn_global_load_lds(
        (const __attribute__((address_space(1))) unsigned int*)g,
        (__attribute__((address_space(3))) unsigned int*)l,
        16, 0, 0);
}

// ---------------------------------------------------------------------------
// Ledger (what moved, what didn't):
//  - r0: gemm2 8-wave 64x32, 1 barrier/iter: 50us, 27% MfmaUtil. Best K-loop.
//  - r2: 4-wave 64x64 + swizzle: neutral (51.6). LDS BW not the limit.
//  - r3: depth-2 counted vmcnt, monolithic body: neutral (52.6). T4 needs T3.
//  - r5: software grid barrier at exact-capacity: +80us. OFF LIMITS.
//  - r6: 2-phase rhythm w/ only 4 MFMA/phase + 3 barriers/K32: 57us (WORSE).
//    m201's template has 16 MFMA/phase; 64x32 wave tiles can't feed that.
//  => gemm2 K-loop plateau 50-57us across ALL schedule variants. Moratorium
//     on gemm2 schedule edits; this round attacks gemm1 (never profiled, old
//     4-wave 128x64 structure -- suspected 45-60us) + overlaps the x-cast.
//  - r7: container infra flake (no pytest ran, same signature as r4 which
//    also resubmitted cleanly); r6 design resubmitted unchanged.
//  - Swizzle (verified r2/r3: conflicts 6.29M -> 0): logical 16B chunk c of
//    row r stored at physical c ^ ((r>>1)&3), both-sides.

// prep: 2112 transpose blocks only (x-cast moved into gemm1's dispatch).
//   blocks [0,1056)    -> transpose+cast W  -> WT  [LAT][KPAD]
//   blocks [1056,2112) -> transpose+cast cb -> cosT[LAT][KPAD]
__global__ void prep_kernel(const float* __restrict__ W,
                            const float* __restrict__ cb,
                            unsigned short* __restrict__ WT,
                            unsigned short* __restrict__ cosT,
                            float* __restrict__ maxp) {
    __shared__ float t[64][65];
    const int bid = blockIdx.x;
    const int tid = threadIdx.x;
    if (bid == 0 && tid == 0) *maxp = -__builtin_inff();
    const float* in     = (bid < 1056) ? W  : cb;
    unsigned short* out = (bid < 1056) ? WT : cosT;
    int b2 = (bid < 1056) ? bid : bid - 1056;
    const int c0 = (b2 % 32) * 64;
    const int r0 = (b2 / 32) * 64;
    for (int i = tid; i < 1024; i += 256) {
        int rr = i >> 4;            // 0..63
        int c4 = (i & 15) * 4;      // 0..60
        int r  = r0 + rr;
        float4 v;
        if (r < NFREQ) v = *(const float4*)&in[(size_t)r * LAT + c0 + c4];
        else           v = make_float4(0.f, 0.f, 0.f, 0.f);
        t[rr][c4 + 0] = v.x; t[rr][c4 + 1] = v.y;
        t[rr][c4 + 2] = v.z; t[rr][c4 + 3] = v.w;
    }
    __syncthreads();
    for (int i = tid; i < 1024; i += 256) {
        int cc = i >> 4;            // 0..63: out row
        int r4 = (i & 15) * 4;      // 0..60: out col group
        ushort4 o;
        o.x = f2bf(t[r4 + 0][cc]); o.y = f2bf(t[r4 + 1][cc]);
        o.z = f2bf(t[r4 + 2][cc]); o.w = f2bf(t[r4 + 3][cc]);
        *(ushort4*)&out[(size_t)(c0 + cc) * KPAD + r0 + r4] = o;
    }
}

// ---------------------------------------------------------------------------
// GEMM1 (rebuilt as the proven r0-gemm2 structure, 653 TF class):
// C[m][n] = sum_k A[m][k]*Bt[n][k], bf16 out. 128x128 block tile, 512 thr =
// 8 waves of 64x32, 3-stage circular LDS, vmcnt(2) straddle, swizzle.
// Grid dim3(16, 16+16): y<16 = GEMM (256 blocks = 1/CU), y>=16 = x-cast
// blocks (256 blocks overlap their HBM work with the GEMM's MFMA work --
// separate pipes co-schedule per m114).
template <int N, int K>
__global__ __launch_bounds__(512, 4)
void gemm1_kernel(const unsigned short* __restrict__ A,
                  const unsigned short* __restrict__ Bt,
                  unsigned short* __restrict__ C,
                  const float* __restrict__ x,
                  unsigned short* __restrict__ xb) {
    if (blockIdx.y >= 16) {
        // ---- x-cast: fp32 -> bf16, 8 elems per thread-iter, uint4 stores ----
        const int cb  = (blockIdx.y - 16) * 16 + blockIdx.x;   // 0..255
        const int tid = threadIdx.x;
        const float4* x4 = (const float4*)x;
        uint4* o4 = (uint4*)xb;
        int i = cb * 512 + tid;                                 // uint4 index
#pragma unroll
        for (int it = 0; it < 8; ++it, i += 131072) {
            float4 a = x4[2 * i];
            float4 b = x4[2 * i + 1];
            union { unsigned short us[8]; uint4 v; } p;
            p.us[0] = f2bf(a.x); p.us[1] = f2bf(a.y); p.us[2] = f2bf(a.z); p.us[3] = f2bf(a.w);
            p.us[4] = f2bf(b.x); p.us[5] = f2bf(b.y); p.us[6] = f2bf(b.z); p.us[7] = f2bf(b.w);
            o4[i] = p.v;
        }
        return;
    }

    __shared__ alignas(16) unsigned short As[3][128 * 32];
    __shared__ alignas(16) unsigned short Bs[3][128 * 32];

    const int tid  = threadIdx.x;
    const int wave = tid >> 6;          // 0..7
    const int lane = tid & 63;
    const int wm   = (wave >> 2) * 64;  // m-half
    const int wn   = (wave & 3) * 32;   // n-quarter
    const int quad = lane >> 4;
    const int l16  = lane & 15;

    const int mBase = blockIdx.y * 128;
    const int nBase = blockIdx.x * 128;

    const int srow = lane >> 2;
    const int sk   = (((lane & 3) ^ ((srow >> 1) & 3))) * 8; // swizzled source

    const unsigned short* Ab1 = A  + (size_t)(mBase + wave * 16 + srow) * K + sk;
    const unsigned short* Bb1 = Bt + (size_t)(nBase + wave * 16 + srow) * K + sk;
    const int coff = (wave * 16) * 32;

    const int pc = (quad ^ ((l16 >> 1) & 3)) * 8;            // swizzled frag read

    constexpr int NIT = K / 32;
    gload_lds16(Ab1, &As[0][coff]);
    gload_lds16(Bb1, &Bs[0][coff]);

    f32x4 acc[4][2] = {};
    int bc = 0;
    for (int j = 0; j < NIT; ++j) {
        const int bn = (bc == 2) ? 0 : bc + 1;
        if (j + 1 < NIT) {
            const int k0 = (j + 1) * 32;
            gload_lds16(Ab1 + k0, &As[bn][coff]);
            gload_lds16(Bb1 + k0, &Bs[bn][coff]);
            asm volatile("s_waitcnt vmcnt(2)\n\ts_barrier" ::: "memory");
        } else {
            asm volatile("s_waitcnt vmcnt(0)\n\ts_barrier" ::: "memory");
        }
        bf16x8 af[4], bfr[2];
#pragma unroll
        for (int mi = 0; mi < 4; ++mi)
            af[mi] = *(const bf16x8*)&As[bc][(wm + mi * 16 + l16) * 32 + pc];
#pragma unroll
        for (int ni = 0; ni < 2; ++ni)
            bfr[ni] = *(const bf16x8*)&Bs[bc][(wn + ni * 16 + l16) * 32 + pc];
#pragma unroll
        for (int mi = 0; mi < 4; ++mi)
#pragma unroll
            for (int ni = 0; ni < 2; ++ni)
                acc[mi][ni] = __builtin_amdgcn_mfma_f32_16x16x32_bf16(
                    af[mi], bfr[ni], acc[mi][ni], 0, 0, 0);
        bc = bn;
    }

    // C/D layout: col = lane&15, row = quad*4 + reg
#pragma unroll
    for (int mi = 0; mi < 4; ++mi)
#pragma unroll
        for (int ni = 0; ni < 2; ++ni) {
            int col = nBase + wn + ni * 16 + l16;
#pragma unroll
            for (int r = 0; r < 4; ++r) {
                int row = mBase + wm + mi * 16 + quad * 4 + r;
                C[(size_t)row * N + col] = f2bf(acc[mi][ni][r]);
            }
        }
}

// ---------------------------------------------------------------------------
// GEMM2: exact r0 geometry (fastest measured: 512 thr = 8 waves of 64x32,
// 16 waves/CU, 1 vmcnt+barrier per iter) + verified swizzle. fp32 out +
// fused global max (wave-reduce -> LDS -> ONE atomic per block).
template <int N, int K>
__global__ __launch_bounds__(512, 4)
void gemm2_kernel(const unsigned short* __restrict__ A,
                  const unsigned short* __restrict__ Bt,
                  float* __restrict__ C,
                  float* __restrict__ maxp) {
    __shared__ alignas(16) unsigned short As[3][128 * 32];
    __shared__ alignas(16) unsigned short Bs[3][128 * 32];
    __shared__ float redbuf[8];

    const int tid  = threadIdx.x;
    const int wave = tid >> 6;          // 0..7
    const int lane = tid & 63;
    const int wm   = (wave >> 2) * 64;  // m-half
    const int wn   = (wave & 3) * 32;   // n-quarter
    const int quad = lane >> 4;
    const int l16  = lane & 15;

    const int mBase = blockIdx.y * 128;
    const int nBase = blockIdx.x * 128;

    const int srow = lane >> 2;
    const int sk   = (((lane & 3) ^ ((srow >> 1) & 3))) * 8; // swizzled source

    const unsigned short* Ab1 = A  + (size_t)(mBase + wave * 16 + srow) * K + sk;
    const unsigned short* Bb1 = Bt + (size_t)(nBase + wave * 16 + srow) * K + sk;
    const int coff = (wave * 16) * 32;

    const int pc = (quad ^ ((l16 >> 1) & 3)) * 8;            // swizzled frag read

    constexpr int NIT = K / 32;
    gload_lds16(Ab1, &As[0][coff]);
    gload_lds16(Bb1, &Bs[0][coff]);

    f32x4 acc[4][2] = {};
    int bc = 0;
    for (int j = 0; j < NIT; ++j) {
        const int bn = (bc == 2) ? 0 : bc + 1;
        if (j + 1 < NIT) {
            const int k0 = (j + 1) * 32;
            gload_lds16(Ab1 + k0, &As[bn][coff]);
            gload_lds16(Bb1 + k0, &Bs[bn][coff]);
            asm volatile("s_waitcnt vmcnt(2)\n\ts_barrier" ::: "memory");
        } else {
            asm volatile("s_waitcnt vmcnt(0)\n\ts_barrier" ::: "memory");
        }
        bf16x8 af[4], bfr[2];
#pragma unroll
        for (int mi = 0; mi < 4; ++mi)
            af[mi] = *(const bf16x8*)&As[bc][(wm + mi * 16 + l16) * 32 + pc];
#pragma unroll
        for (int ni = 0; ni < 2; ++ni)
            bfr[ni] = *(const bf16x8*)&Bs[bc][(wn + ni * 16 + l16) * 32 + pc];
#pragma unroll
        for (int mi = 0; mi < 4; ++mi)
#pragma unroll
            for (int ni = 0; ni < 2; ++ni)
                acc[mi][ni] = __builtin_amdgcn_mfma_f32_16x16x32_bf16(
                    af[mi], bfr[ni], acc[mi][ni], 0, 0, 0);
        bc = bn;
    }

    // epilogue: fp32 store + block max + one atomic
    float vmax = -__builtin_inff();
#pragma unroll
    for (int mi = 0; mi < 4; ++mi)
#pragma unroll
        for (int ni = 0; ni < 2; ++ni) {
            int col = nBase + wn + ni * 16 + l16;
#pragma unroll
            for (int r = 0; r < 4; ++r) {
                int row = mBase + wm + mi * 16 + quad * 4 + r;
                float v = acc[mi][ni][r];
                C[(size_t)row * N + col] = v;
                vmax = fmaxf(vmax, v);
            }
        }
#pragma unroll
    for (int off = 32; off > 0; off >>= 1)
        vmax = fmaxf(vmax, __shfl_xor(vmax, off));
    if (lane == 0) redbuf[wave] = vmax;
    __syncthreads();
    if (tid == 0) {
        float m = redbuf[0];
#pragma unroll
        for (int w = 1; w < 8; ++w) m = fmaxf(m, redbuf[w]);
        if (m >= 0.0f) atomicMax((int*)maxp, __float_as_int(m));
        else           atomicMin((unsigned int*)maxp, __float_as_uint(m));
    }
}

// ---------------------------------------------------------------------------
__global__ void scale_kernel(float* __restrict__ out, const float* __restrict__ maxp) {
    int i = blockIdx.x * blockDim.x + threadIdx.x;
    float inv = 1.0f / (*maxp);
    float4* o4 = (float4*)out;
    float4 v = o4[i];
    v.x *= inv; v.y *= inv; v.z *= inv; v.w *= inv;
    o4[i] = v;
}

// ---------------------------------------------------------------------------
extern "C" void kernel_launch(void* const* d_in, const int* in_sizes, int n_in,
                              void* d_out, int out_size, void* d_ws, size_t ws_size,
                              hipStream_t stream) {
    const float* x  = (const float*)d_in[0];  // (4096, 2048)
    const float* W  = (const float*)d_in[1];  // (2074, 2048)
    const float* cb = (const float*)d_in[2];  // (2074, 2048)

    char* ws = (char*)d_ws;
    unsigned short* xb   = (unsigned short*)ws;                                   // [4096][2048] bf16
    unsigned short* WT   = (unsigned short*)(ws + (size_t)BATCH * LAT * 2);       // [2048][2112] bf16
    unsigned short* cosT = (unsigned short*)((char*)WT + (size_t)LAT * KPAD * 2);
    unsigned short* C1   = (unsigned short*)((char*)cosT + (size_t)LAT * KPAD * 2); // [2048][2048] bf16
    float*          maxp = (float*)((char*)C1 + (size_t)LAT * LAT * 2);
    float*          out  = (float*)d_out;

    // 1. prep: transpose+cast W and cos_basis (+init max)
    prep_kernel<<<2 * 1056, 256, 0, stream>>>(W, cb, WT, cosT, maxp);

    // 2. C1[l2][l1] = sum_f cosT[l2,f] * WT[l1,f]   (128x128 tiles, 256 GEMM
    //    blocks) + 256 x-cast blocks overlapped in the same dispatch
    gemm1_kernel<LAT, KPAD>
        <<<dim3(16, 32), 512, 0, stream>>>(cosT, WT, C1, x, xb);

    // 3. out[b][l2] = sum_l1 xb[b][l1] * C1[l2][l1]  (128x128, 512 thr, 8 waves,
    //    r0 schedule + swizzle, fused max)
    gemm2_kernel<LAT, LAT>
        <<<dim3(LAT / 128, BATCH / 128), 512, 0, stream>>>(xb, C1, out, maxp);

    // 4. out /= max
    scale_kernel<<<(out_size / 4) / 256, 256, 0, stream>>>(out, maxp);
}